// Round 5
// baseline (183.179 us; speedup 1.0000x reference)
//
#include <hip/hip_runtime.h>
#include <hip/hip_bf16.h>

// Problem constants
#define BN_NODES 4096      // B*N = 8*512
#define KNN 16
#define C_POOL 256
#define G_DIM 128
#define IN_DIM 384         // C_POOL + G_DIM
#define L_DIM 512
#define OUT_STRIDE 1920    // 384 + 3*512

#define X0_OFF 0
#define X1_OFF 384
#define X2_OFF 896
#define X3_OFF 1408

typedef __attribute__((ext_vector_type(8))) __bf16 bf16x8;
typedef __attribute__((ext_vector_type(4))) float floatx4;

static __device__ __forceinline__ ushort f2bf(float v) {
  return __builtin_bit_cast(ushort, __float2bfloat16(v));
}
static __device__ __forceinline__ float bf2f(ushort u) {
  return __builtin_bit_cast(float, ((unsigned)u) << 16);
}
static __device__ __forceinline__ void gld_lds(const ushort* g, ushort* l) {
  __builtin_amdgcn_global_load_lds(
      (const __attribute__((address_space(1))) void*)g,
      (__attribute__((address_space(3))) void*)l, 16, 0, 0);
}

// ---------------------------------------------------------------------------
// Kernel 1 (prep): blocks [0,512): node_feat (8 nodes/block);
//                  blocks [512,1920): wconv for all 3 layers.
// node_feat: x0 fp32 slice of out + bf16 Xb0 (stride IN_DIM).
// wconv: Wb_l[j][k] = (j<512) ? W[j][k] : W[j-512][K+k], bf16.
// ---------------------------------------------------------------------------
__global__ __launch_bounds__(256) void prep_kernel(
    const float* __restrict__ rois, const float* __restrict__ pooled,
    const float* __restrict__ gW1, const float* __restrict__ gb1,
    const float* __restrict__ gW2, const float* __restrict__ gb2,
    const float* __restrict__ W0, const float* __restrict__ W1,
    const float* __restrict__ W2, float* __restrict__ out,
    ushort* __restrict__ Xb0, ushort* __restrict__ Wb0,
    ushort* __restrict__ Wb1, ushort* __restrict__ Wb2) {
  const int t = threadIdx.x;
  if (blockIdx.x >= 512) {
    // ---- wconv part ----
    int wi = blockIdx.x - 512;
    const float* W;
    ushort* Wb;
    int K, base;
    if (wi < 384) {
      W = W0; Wb = Wb0; K = IN_DIM; base = wi;
    } else if (wi < 896) {
      W = W1; Wb = Wb1; K = L_DIM; base = wi - 384;
    } else {
      W = W2; Wb = Wb2; K = L_DIM; base = wi - 896;
    }
    int elem = base * 1024 + t * 4;
    int j = elem / K;          // K is 384 or 512; compiler emits magic-mul
    int k = elem - j * K;      // 4-aligned, k+3 < K (K % 4 == 0)
    const float* srcp = (j < 512) ? W + (size_t)j * (2 * K) + k
                                  : W + (size_t)(j - 512) * (2 * K) + K + k;
    ushort4 pk;
    pk.x = f2bf(srcp[0]);
    pk.y = f2bf(srcp[1]);
    pk.z = f2bf(srcp[2]);
    pk.w = f2bf(srcp[3]);
    *(ushort4*)(Wb + (size_t)j * K + k) = pk;
    return;
  }
  // ---- node_feat part: 8 nodes per block ----
  const int nb = blockIdx.x * 8;
  const int c = t & 127;
  const int nh = t >> 7;
  __shared__ float rs[8 * 7];
  __shared__ __align__(16) float h1[8][G_DIM];
  if (t < 56) rs[t] = rois[(size_t)nb * 7 + t];
  __syncthreads();
  {
    float w1[7];
#pragma unroll
    for (int i = 0; i < 7; i++) w1[i] = gW1[c * 7 + i];
    float b1 = gb1[c];
#pragma unroll
    for (int n = nh * 4; n < nh * 4 + 4; n++) {
      float a = b1;
#pragma unroll
      for (int i = 0; i < 7; i++) a += rs[n * 7 + i] * w1[i];
      h1[n][c] = fmaxf(a, 0.f);
    }
  }
  __syncthreads();
  float acc[4];
  {
    float b2 = gb2[c];
#pragma unroll
    for (int n = 0; n < 4; n++) acc[n] = b2;
    const float4* w4 = (const float4*)(gW2 + (size_t)c * G_DIM);
#pragma unroll 4
    for (int kc = 0; kc < G_DIM / 4; kc++) {
      float4 wv = w4[kc];
#pragma unroll
      for (int n = 0; n < 4; n++) {
        float4 hv = ((const float4*)h1[nh * 4 + n])[kc];
        acc[n] += wv.x * hv.x + wv.y * hv.y + wv.z * hv.z + wv.w * hv.w;
      }
    }
  }
#pragma unroll
  for (int n = 0; n < 4; n++) {
    int node = nb + nh * 4 + n;
    float g = fmaxf(acc[n], 0.f);
    const float* prow = pooled + (size_t)node * C_POOL;
    float p0 = prow[c], p1 = prow[G_DIM + c];
    float* orow = out + (size_t)node * OUT_STRIDE;
    orow[c] = p0;
    orow[G_DIM + c] = p1;
    orow[C_POOL + c] = g;
    ushort* xrow = Xb0 + (size_t)node * IN_DIM;
    xrow[c] = f2bf(p0);
    xrow[G_DIM + c] = f2bf(p1);
    xrow[C_POOL + c] = f2bf(g);
  }
}

// ---------------------------------------------------------------------------
// Kernel 2 (fused layer): block = (stripe 0..31, batch 0..7).
// Computes P,Q stripe (16 P-chans + 16 Q-chans) for all 512 batch rows into
// LDS via bf16 MFMA, then does edge max+relu from LDS and writes
// out fp32 slice + Xout bf16.  All LDS tiles in MFMA fragment order
// (tile = 16 rows x 32 k, lane l holds [row=l&15][k=(l>>4)*8..+7]).
//   sA tile ta = rt*2 + ks   (rt 0..31 covers 512 rows, ks = k-half of 64)
//   sB tile tb = kt*2 + ct   (kt = K/32 tiles, ct: 0=P rows, 1=Q rows)
// Grid 32x8 = 256 blocks = 1/CU.  LDS = 64+32+32 = 128 KB.
// ---------------------------------------------------------------------------
__global__ __launch_bounds__(256) void layer_kernel(
    const ushort* __restrict__ Xin, int ldx, int K,
    const ushort* __restrict__ Wb, const int* __restrict__ src,
    const float* __restrict__ bias, float* __restrict__ out, int out_off,
    ushort* __restrict__ Xout, int write_x) {
  __shared__ ushort sA[512 * 64];      // 64 KB
  __shared__ ushort sB[32 * 512];      // 32 KB (max K=512)
  __shared__ ushort sPQ[512 * 32];     // 32 KB
  const int stripe = blockIdx.x;
  const int b = blockIdx.y;
  const int tid = threadIdx.x;
  const int lane = tid & 63;
  const int w = tid >> 6;
  const int fr = lane & 15;
  const int kc = lane >> 4;

  const ushort* Ab = Xin + (size_t)(b * 512) * ldx;

  // stage B for the whole K extent (never overwritten)
  const int nbt = (K >> 5) * 2;  // 24 or 32 tiles
  for (int r = 0; r < nbt / 4; r++) {
    int tb = w + 4 * r;
    int kt = tb >> 1, ct = tb & 1;
    const ushort* g =
        Wb + (size_t)(ct * 512 + stripe * 16 + fr) * K + kt * 32 + kc * 8;
    gld_lds(g, &sB[tb * 512 + lane * 8]);
  }

  floatx4 acc[8][2];
#pragma unroll
  for (int i = 0; i < 8; i++)
#pragma unroll
    for (int j = 0; j < 2; j++) acc[i][j] = (floatx4){0.f, 0.f, 0.f, 0.f};

  for (int k0 = 0; k0 < K; k0 += 64) {
#pragma unroll
    for (int r = 0; r < 16; r++) {
      int ta = w + 4 * r;
      int rt = ta >> 1, ks = ta & 1;
      const ushort* g =
          Ab + (size_t)(rt * 16 + fr) * ldx + k0 + ks * 32 + kc * 8;
      gld_lds(g, &sA[ta * 512 + lane * 8]);
    }
    __syncthreads();
#pragma unroll
    for (int ks = 0; ks < 2; ks++) {
      int ktg = (k0 >> 5) + ks;
      bf16x8 bfv[2];
#pragma unroll
      for (int ct = 0; ct < 2; ct++)
        bfv[ct] = *(const bf16x8*)&sB[(ktg * 2 + ct) * 512 + lane * 8];
#pragma unroll
      for (int rl = 0; rl < 8; rl++) {
        bf16x8 av = *(const bf16x8*)&sA[((w * 8 + rl) * 2 + ks) * 512 + lane * 8];
#pragma unroll
        for (int ct = 0; ct < 2; ct++)
          acc[rl][ct] = __builtin_amdgcn_mfma_f32_16x16x32_bf16(av, bfv[ct],
                                                                acc[rl][ct], 0,
                                                                0, 0);
      }
    }
    __syncthreads();
  }

  // epilogue: acc -> sPQ (C/D layout: row = kc*4 + reg, col = fr)
#pragma unroll
  for (int rl = 0; rl < 8; rl++)
#pragma unroll
    for (int ct = 0; ct < 2; ct++)
#pragma unroll
      for (int r = 0; r < 4; r++)
        sPQ[((w * 8 + rl) * 16 + kc * 4 + r) * 32 + ct * 16 + fr] =
            f2bf(acc[rl][ct][r]);
  __syncthreads();

  // edge phase: thread = (cq = tid&3 -> 4 channels, slice = tid>>2 -> 8 nodes)
  const int cq = tid & 3;
  const int slice = tid >> 2;
  const int c0 = stripe * 16;
  const float4 bb = *(const float4*)&bias[c0 + cq * 4];
#pragma unroll
  for (int i = 0; i < 8; i++) {
    int n = slice * 8 + i;
    const int* sp = src + (size_t)(b * 512 + n) * KNN;
    float mx = -1e30f, my = -1e30f, mz = -1e30f, mw = -1e30f;
#pragma unroll
    for (int k = 0; k < KNN; k++) {
      int sl = sp[k] - b * 512;
      ushort4 u = *(const ushort4*)&sPQ[sl * 32 + cq * 4];
      mx = fmaxf(mx, bf2f(u.x));
      my = fmaxf(my, bf2f(u.y));
      mz = fmaxf(mz, bf2f(u.z));
      mw = fmaxf(mw, bf2f(u.w));
    }
    ushort4 pu = *(const ushort4*)&sPQ[n * 32 + cq * 4];
    ushort4 qu = *(const ushort4*)&sPQ[n * 32 + 16 + cq * 4];
    float4 res;
    res.x = fmaxf(mx - bf2f(pu.x) + bf2f(qu.x) + bb.x, 0.f);
    res.y = fmaxf(my - bf2f(pu.y) + bf2f(qu.y) + bb.y, 0.f);
    res.z = fmaxf(mz - bf2f(pu.z) + bf2f(qu.z) + bb.z, 0.f);
    res.w = fmaxf(mw - bf2f(pu.w) + bf2f(qu.w) + bb.w, 0.f);
    size_t node = (size_t)(b * 512 + n);
    *(float4*)(out + node * OUT_STRIDE + out_off + c0 + cq * 4) = res;
    if (write_x) {
      ushort4 pk;
      pk.x = f2bf(res.x);
      pk.y = f2bf(res.y);
      pk.z = f2bf(res.z);
      pk.w = f2bf(res.w);
      *(ushort4*)(Xout + node * L_DIM + c0 + cq * 4) = pk;
    }
  }
}

extern "C" void kernel_launch(void* const* d_in, const int* in_sizes, int n_in,
                              void* d_out, int out_size, void* d_ws,
                              size_t ws_size, hipStream_t stream) {
  const float* rois = (const float*)d_in[0];
  const float* pooled = (const float*)d_in[1];
  const int* edge_index = (const int*)d_in[2];
  const float* gW1 = (const float*)d_in[3];
  const float* gb1 = (const float*)d_in[4];
  const float* gW2 = (const float*)d_in[5];
  const float* gb2 = (const float*)d_in[6];
  const float* fcW[3] = {(const float*)d_in[7], (const float*)d_in[9],
                         (const float*)d_in[11]};
  const float* fcb[3] = {(const float*)d_in[8], (const float*)d_in[10],
                         (const float*)d_in[12]};
  float* out = (float*)d_out;
  const int* src = edge_index;  // dst[e] == e/16 by construction

  // workspace layout (bytes):
  //   Xb0 : 4096*384 bf16 = 3 MB   @ 0
  //   Xb1 : 4096*512 bf16 = 4 MB   @ 4 MB
  //   Xb2 : 4096*512 bf16 = 4 MB   @ 8 MB
  //   Wb0 : 1024*384 bf16          @ 12 MB
  //   Wb1 : 1024*512 bf16          @ 13 MB
  //   Wb2 : 1024*512 bf16          @ 14 MB
  char* ws = (char*)d_ws;
  ushort* Xb0 = (ushort*)ws;
  ushort* Xb1 = (ushort*)(ws + (size_t)4 * 1024 * 1024);
  ushort* Xb2 = (ushort*)(ws + (size_t)8 * 1024 * 1024);
  ushort* Wb0 = (ushort*)(ws + (size_t)12 * 1024 * 1024);
  ushort* Wb1 = (ushort*)(ws + (size_t)13 * 1024 * 1024);
  ushort* Wb2 = (ushort*)(ws + (size_t)14 * 1024 * 1024);

  prep_kernel<<<1920, 256, 0, stream>>>(rois, pooled, gW1, gb1, gW2, gb2,
                                        fcW[0], fcW[1], fcW[2], out, Xb0, Wb0,
                                        Wb1, Wb2);
  layer_kernel<<<dim3(32, 8), 256, 0, stream>>>(Xb0, IN_DIM, IN_DIM, Wb0, src,
                                                fcb[0], out, X1_OFF, Xb1, 1);
  layer_kernel<<<dim3(32, 8), 256, 0, stream>>>(Xb1, L_DIM, L_DIM, Wb1, src,
                                                fcb[1], out, X2_OFF, Xb2, 1);
  layer_kernel<<<dim3(32, 8), 256, 0, stream>>>(Xb2, L_DIM, L_DIM, Wb2, src,
                                                fcb[2], out, X3_OFF, nullptr,
                                                0);
}

// Round 6
// 170.093 us; speedup vs baseline: 1.0769x; 1.0769x over previous
//
#include <hip/hip_runtime.h>
#include <hip/hip_bf16.h>

// Problem constants
#define BN_NODES 4096      // B*N = 8*512
#define KNN 16
#define C_POOL 256
#define G_DIM 128
#define IN_DIM 384         // C_POOL + G_DIM
#define L_DIM 512
#define OUT_STRIDE 1920    // 384 + 3*512

#define X0_OFF 0
#define X1_OFF 384
#define X2_OFF 896
#define X3_OFF 1408

typedef __attribute__((ext_vector_type(8))) __bf16 bf16x8;
typedef __attribute__((ext_vector_type(4))) float floatx4;

static __device__ __forceinline__ ushort f2bf(float v) {
  return __builtin_bit_cast(ushort, __float2bfloat16(v));
}
static __device__ __forceinline__ float bf2f(ushort u) {
  return __builtin_bit_cast(float, ((unsigned)u) << 16);
}
static __device__ __forceinline__ void gld_lds(const ushort* g, ushort* l) {
  __builtin_amdgcn_global_load_lds(
      (const __attribute__((address_space(1))) void*)g,
      (__attribute__((address_space(3))) void*)l, 16, 0, 0);
}

// ---------------------------------------------------------------------------
// Kernel 1 (prep): blocks [0,512): node_feat (8 nodes/block);
//                  blocks [512,1920): wconv for all 3 layers.
// ---------------------------------------------------------------------------
__global__ __launch_bounds__(256) void prep_kernel(
    const float* __restrict__ rois, const float* __restrict__ pooled,
    const float* __restrict__ gW1, const float* __restrict__ gb1,
    const float* __restrict__ gW2, const float* __restrict__ gb2,
    const float* __restrict__ W0, const float* __restrict__ W1,
    const float* __restrict__ W2, float* __restrict__ out,
    ushort* __restrict__ Xb0, ushort* __restrict__ Wb0,
    ushort* __restrict__ Wb1, ushort* __restrict__ Wb2) {
  const int t = threadIdx.x;
  if (blockIdx.x >= 512) {
    int wi = blockIdx.x - 512;
    const float* W;
    ushort* Wb;
    int K, base;
    if (wi < 384) {
      W = W0; Wb = Wb0; K = IN_DIM; base = wi;
    } else if (wi < 896) {
      W = W1; Wb = Wb1; K = L_DIM; base = wi - 384;
    } else {
      W = W2; Wb = Wb2; K = L_DIM; base = wi - 896;
    }
    int elem = base * 1024 + t * 4;
    int j = elem / K;
    int k = elem - j * K;
    const float* srcp = (j < 512) ? W + (size_t)j * (2 * K) + k
                                  : W + (size_t)(j - 512) * (2 * K) + K + k;
    ushort4 pk;
    pk.x = f2bf(srcp[0]);
    pk.y = f2bf(srcp[1]);
    pk.z = f2bf(srcp[2]);
    pk.w = f2bf(srcp[3]);
    *(ushort4*)(Wb + (size_t)j * K + k) = pk;
    return;
  }
  const int nb = blockIdx.x * 8;
  const int c = t & 127;
  const int nh = t >> 7;
  __shared__ float rs[8 * 7];
  __shared__ __align__(16) float h1[8][G_DIM];
  if (t < 56) rs[t] = rois[(size_t)nb * 7 + t];
  __syncthreads();
  {
    float w1[7];
#pragma unroll
    for (int i = 0; i < 7; i++) w1[i] = gW1[c * 7 + i];
    float b1 = gb1[c];
#pragma unroll
    for (int n = nh * 4; n < nh * 4 + 4; n++) {
      float a = b1;
#pragma unroll
      for (int i = 0; i < 7; i++) a += rs[n * 7 + i] * w1[i];
      h1[n][c] = fmaxf(a, 0.f);
    }
  }
  __syncthreads();
  float acc[4];
  {
    float b2 = gb2[c];
#pragma unroll
    for (int n = 0; n < 4; n++) acc[n] = b2;
    const float4* w4 = (const float4*)(gW2 + (size_t)c * G_DIM);
#pragma unroll 4
    for (int kc = 0; kc < G_DIM / 4; kc++) {
      float4 wv = w4[kc];
#pragma unroll
      for (int n = 0; n < 4; n++) {
        float4 hv = ((const float4*)h1[nh * 4 + n])[kc];
        acc[n] += wv.x * hv.x + wv.y * hv.y + wv.z * hv.z + wv.w * hv.w;
      }
    }
  }
#pragma unroll
  for (int n = 0; n < 4; n++) {
    int node = nb + nh * 4 + n;
    float g = fmaxf(acc[n], 0.f);
    const float* prow = pooled + (size_t)node * C_POOL;
    float p0 = prow[c], p1 = prow[G_DIM + c];
    float* orow = out + (size_t)node * OUT_STRIDE;
    orow[c] = p0;
    orow[G_DIM + c] = p1;
    orow[C_POOL + c] = g;
    ushort* xrow = Xb0 + (size_t)node * IN_DIM;
    xrow[c] = f2bf(p0);
    xrow[G_DIM + c] = f2bf(p1);
    xrow[C_POOL + c] = f2bf(g);
  }
}

// ---------------------------------------------------------------------------
// Kernel 2: bf16 MFMA GEMM  PQb[4096 x 1024] = Xb[4096 x K] @ Wb[1024 x K]^T
// Tile 128x64, BK=64, 512 threads = 8 waves (4x2), wave = 32x32 (2x2 tiles).
// 2 blocks/CU x 8 waves = 16 waves/CU = 4/SIMD (latency hiding).
// LDS in MFMA fragment order: 16x32 tile = 64 lane-fragments contiguous
// (1 KB/tile); frag ds_read_b128 at tile_base + lane*16 -> conflict-free.
//   sA tile ta = rt*2 + ks (rt 0..7), sB tile tb = ct*2 + ks (ct 0..3).
// ---------------------------------------------------------------------------
__global__ __launch_bounds__(512) void mfma_gemm_kernel(
    const ushort* __restrict__ Xb, const ushort* __restrict__ Wb, int K,
    ushort* __restrict__ PQb) {
  __shared__ ushort sA[128 * 64];  // 16 KB, 16 tiles
  __shared__ ushort sB[64 * 64];   // 8 KB, 8 tiles
  const int tid = threadIdx.x;
  const int lane = tid & 63;
  const int w = tid >> 6;          // wave 0..7
  const int wm = w >> 1;           // 0..3 (32-row band)
  const int wn = w & 1;            // 0..1 (32-col band)
  const int fr = lane & 15;
  const int kc = lane >> 4;
  const int bm = blockIdx.x, bn = blockIdx.y;

  floatx4 acc[2][2];
#pragma unroll
  for (int i = 0; i < 2; i++)
#pragma unroll
    for (int j = 0; j < 2; j++) acc[i][j] = (floatx4){0.f, 0.f, 0.f, 0.f};

  for (int k0 = 0; k0 < K; k0 += 64) {
#pragma unroll
    for (int r = 0; r < 2; r++) {
      int ta = w + r * 8;          // wave-uniform
      int rt = ta >> 1, ks = ta & 1;
      const ushort* ga =
          Xb + (size_t)(bm * 128 + rt * 16 + fr) * K + k0 + ks * 32 + kc * 8;
      gld_lds(ga, &sA[ta * 512 + lane * 8]);
    }
    {
      int tb = w;                  // 8 tiles, one per wave
      int ct = tb >> 1, ks = tb & 1;
      const ushort* gb =
          Wb + (size_t)(bn * 64 + ct * 16 + fr) * K + k0 + ks * 32 + kc * 8;
      gld_lds(gb, &sB[tb * 512 + lane * 8]);
    }
    __syncthreads();
#pragma unroll
    for (int ks = 0; ks < 2; ks++) {
      bf16x8 af[2], bf[2];
#pragma unroll
      for (int i = 0; i < 2; i++)
        af[i] = *(const bf16x8*)&sA[((wm * 2 + i) * 2 + ks) * 512 + lane * 8];
#pragma unroll
      for (int j = 0; j < 2; j++)
        bf[j] = *(const bf16x8*)&sB[((wn * 2 + j) * 2 + ks) * 512 + lane * 8];
#pragma unroll
      for (int i = 0; i < 2; i++)
#pragma unroll
        for (int j = 0; j < 2; j++)
          acc[i][j] = __builtin_amdgcn_mfma_f32_16x16x32_bf16(af[i], bf[j],
                                                              acc[i][j], 0, 0,
                                                              0);
    }
    __syncthreads();
  }

  // C/D layout: col = fr, row = kc*4 + reg (m89-verified)
  const int rowB = bm * 128 + wm * 32 + kc * 4;
  const int colB = bn * 64 + wn * 32 + fr;
#pragma unroll
  for (int i = 0; i < 2; i++)
#pragma unroll
    for (int j = 0; j < 2; j++)
#pragma unroll
      for (int r = 0; r < 4; r++)
        PQb[(size_t)(rowB + i * 16 + r) * 1024 + colB + j * 16] =
            f2bf(acc[i][j][r]);
}

// ---------------------------------------------------------------------------
// Kernel 3: edge gather + max + relu (bf16 PQ); writes fp32 out slice + Xb
//   x_new[n][c] = relu( max_k P[src[n*16+k]][c] + Q[n][c] - P[n][c] + b[c] )
// grid: 4096 blocks, 128 threads (4 channels/thread)
// ---------------------------------------------------------------------------
__global__ __launch_bounds__(128) void edge_kernel(
    const ushort* __restrict__ PQb, const int* __restrict__ src,
    const float* __restrict__ bias, float* __restrict__ out, int out_off,
    ushort* __restrict__ Xb) {
  int n = blockIdx.x;
  int t = threadIdx.x;
  __shared__ int s[KNN];
  if (t < KNN) s[t] = src[n * KNN + t];
  __syncthreads();
  const ushort* row = PQb + (size_t)n * 1024;
  ushort4 pu = *(const ushort4*)(row + t * 4);
  ushort4 qu = *(const ushort4*)(row + 512 + t * 4);
  float4 bb = ((const float4*)bias)[t];
  float bx = bf2f(qu.x) - bf2f(pu.x) + bb.x;
  float by = bf2f(qu.y) - bf2f(pu.y) + bb.y;
  float bz = bf2f(qu.z) - bf2f(pu.z) + bb.z;
  float bw = bf2f(qu.w) - bf2f(pu.w) + bb.w;
  float mx = -1e30f, my = -1e30f, mz = -1e30f, mw = -1e30f;
#pragma unroll
  for (int k = 0; k < KNN; k++) {
    ushort4 u = *(const ushort4*)(PQb + (size_t)s[k] * 1024 + t * 4);
    mx = fmaxf(mx, bf2f(u.x));
    my = fmaxf(my, bf2f(u.y));
    mz = fmaxf(mz, bf2f(u.z));
    mw = fmaxf(mw, bf2f(u.w));
  }
  float4 res;
  res.x = fmaxf(mx + bx, 0.f);
  res.y = fmaxf(my + by, 0.f);
  res.z = fmaxf(mz + bz, 0.f);
  res.w = fmaxf(mw + bw, 0.f);
  float* orow = out + (size_t)n * OUT_STRIDE + out_off;
  ((float4*)orow)[t] = res;
  ushort4 pk;
  pk.x = f2bf(res.x);
  pk.y = f2bf(res.y);
  pk.z = f2bf(res.z);
  pk.w = f2bf(res.w);
  ((ushort4*)(Xb + (size_t)n * L_DIM))[t] = pk;
}

extern "C" void kernel_launch(void* const* d_in, const int* in_sizes, int n_in,
                              void* d_out, int out_size, void* d_ws,
                              size_t ws_size, hipStream_t stream) {
  const float* rois = (const float*)d_in[0];
  const float* pooled = (const float*)d_in[1];
  const int* edge_index = (const int*)d_in[2];
  const float* gW1 = (const float*)d_in[3];
  const float* gb1 = (const float*)d_in[4];
  const float* gW2 = (const float*)d_in[5];
  const float* gb2 = (const float*)d_in[6];
  const float* fcW[3] = {(const float*)d_in[7], (const float*)d_in[9],
                         (const float*)d_in[11]};
  const float* fcb[3] = {(const float*)d_in[8], (const float*)d_in[10],
                         (const float*)d_in[12]};
  float* out = (float*)d_out;
  const int* src = edge_index;  // dst[e] == e/16 by construction

  // workspace layout (bytes):
  //   PQb : 4096*1024 bf16 = 8 MB  @ 0
  //   Xb  : 4096*512  bf16 = 4 MB  @ 8 MB   (stride IN_DIM for x0, L_DIM after)
  //   Wb0 : 1024*384  bf16         @ 12 MB
  //   Wb1 : 1024*512  bf16         @ 13 MB
  //   Wb2 : 1024*512  bf16         @ 14 MB
  char* ws = (char*)d_ws;
  ushort* PQb = (ushort*)ws;
  ushort* Xb = (ushort*)(ws + (size_t)8 * 1024 * 1024);
  ushort* Wb[3] = {(ushort*)(ws + (size_t)12 * 1024 * 1024),
                   (ushort*)(ws + (size_t)13 * 1024 * 1024),
                   (ushort*)(ws + (size_t)14 * 1024 * 1024)};

  prep_kernel<<<1920, 256, 0, stream>>>(rois, pooled, gW1, gb1, gW2, gb2,
                                        fcW[0], fcW[1], fcW[2], out, Xb, Wb[0],
                                        Wb[1], Wb[2]);

  const int out_off[3] = {X1_OFF, X2_OFF, X3_OFF};
  const int Kdim[3] = {IN_DIM, L_DIM, L_DIM};

  for (int l = 0; l < 3; l++) {
    mfma_gemm_kernel<<<dim3(32, 16), 512, 0, stream>>>(Xb, Wb[l], Kdim[l],
                                                       PQb);
    edge_kernel<<<BN_NODES, 128, 0, stream>>>(PQb, src, fcb[l], out,
                                              out_off[l], Xb);
  }
}